// Round 2
// baseline (572.526 us; speedup 1.0000x reference)
//
#include <hip/hip_runtime.h>
#include <hip/hip_bf16.h>
#include <stdint.h>

// SpectralNonLocalBlock on MI355X.
// Algebraic restructure:
//   M[b]  = x1[b] @ x0[b]^T            (256x256 Gram, K=16384)   -- K1 (split-K + reduce, hi/lo bf16)
//   f     = Tw M Pw^T + tb*SP[d] + SA[c]*pb ; SA=Tw@s1, SP=Pw@s0+N*pb   -- K2a/K2b (hi/lo bf16)
//   F     = softmax_c(f)                                         -- K2b2
//   G     = F @ g_w ; yb = F @ g_b                               -- K2c
//   y     = G @ x0 + yb ; written directly in torch-scrambled view layout  -- K3a
//   out   = W_w @ y_view + W_b                                   -- K3b
// All MFMA = v_mfma_f32_16x16x32_bf16, gemm_bt style (both operands [row][K]).

typedef __attribute__((ext_vector_type(4))) float f32x4;
typedef __attribute__((ext_vector_type(8))) short s16x8;

#define MFMA16(A,B,C) __builtin_amdgcn_mfma_f32_16x16x32_bf16((A),(B),(C),0,0,0)

__device__ __forceinline__ short f2bf(float f) {
    union { float f; uint32_t u; } v; v.f = f;
    uint32_t r = v.u + 0x7fffu + ((v.u >> 16) & 1u);
    return (short)(r >> 16);
}
__device__ __forceinline__ float bf2f(short h) {
    union { uint32_t u; float f; } v; v.u = ((uint32_t)(uint16_t)h) << 16;
    return v.f;
}
__device__ __forceinline__ s16x8 pack2(f32x4 a, f32x4 b) {
    s16x8 r;
    r[0]=f2bf(a.x); r[1]=f2bf(a.y); r[2]=f2bf(a.z); r[3]=f2bf(a.w);
    r[4]=f2bf(b.x); r[5]=f2bf(b.y); r[6]=f2bf(b.z); r[7]=f2bf(b.w);
    return r;
}
__device__ __forceinline__ void pack2_hl(f32x4 a, f32x4 b, s16x8& hi, s16x8& lo) {
    float v[8] = {a.x,a.y,a.z,a.w,b.x,b.y,b.z,b.w};
#pragma unroll
    for (int i=0;i<8;++i) {
        short h = f2bf(v[i]);
        hi[i] = h;
        lo[i] = f2bf(v[i] - bf2f(h));
    }
}
__device__ __forceinline__ float hsum4(f32x4 v){ return (v.x+v.y)+(v.z+v.w); }

// ---------------- K0: weight prep (g_w transpose->bf16, W_w->bf16, zero s0/s1)
__global__ __launch_bounds__(256) void k0_prep(
    const float* __restrict__ g_w, const float* __restrict__ W_w,
    short* __restrict__ gwT, short* __restrict__ Wwb,
    float* __restrict__ s0, float* __restrict__ s1)
{
    int gid = blockIdx.x * 256 + threadIdx.x;   // 65536
    int d = gid >> 8, e = gid & 255;
    gwT[e*256 + d] = f2bf(g_w[gid]);            // gwT[e][d] = g_w[d][e]
    Wwb[gid] = f2bf(W_w[gid]);
    if (gid < 2048) { s0[gid] = 0.f; s1[gid] = 0.f; }
}

// ---------------- K1: Gram split-K with hi/lo bf16 (hh+hl+lh MFMAs).
// grid = 8b * 16chunk * 4ij (ij fastest)
__global__ __launch_bounds__(256) void k1_gram(
    const float* __restrict__ x0, const float* __restrict__ x1,
    float* __restrict__ partial, float* __restrict__ s0, float* __restrict__ s1)
{
    __shared__ short Ah[128*40], Al[128*40], Bh[128*40], Bl[128*40];
    int bid = blockIdx.x;
    int ij = bid & 3, ch = (bid >> 2) & 15, b = bid >> 6;
    int i0 = (ij >> 1) * 128, j0 = (ij & 1) * 128, k0 = ch * 1024;
    int tid = threadIdx.x;
    int w = tid >> 6, lane = tid & 63;
    int wr = (w >> 1) * 64, wc = (w & 1) * 64;
    int quad = lane >> 4, l16 = lane & 15;
    int srow = tid >> 1, skk = (tid & 1) * 16;

    const float* pa = x1 + (size_t)(b*256 + i0 + srow)*16384 + k0 + skk;
    const float* pb = x0 + (size_t)(b*256 + j0 + srow)*16384 + k0 + skk;

    f32x4 acc[4][4];
#pragma unroll
    for (int i=0;i<4;i++)
#pragma unroll
    for (int j=0;j<4;j++) acc[i][j] = f32x4{0.f,0.f,0.f,0.f};

    float sumA = 0.f, sumB = 0.f;

    for (int s = 0; s < 32; ++s) {
        f32x4 av[4], bv[4];
#pragma unroll
        for (int q=0;q<4;++q) { av[q] = *(const f32x4*)(pa + q*4); bv[q] = *(const f32x4*)(pb + q*4); }
        pa += 32; pb += 32;
#pragma unroll
        for (int q=0;q<4;++q) { sumA += hsum4(av[q]); sumB += hsum4(bv[q]); }
        __syncthreads();
        s16x8 h, l;
        pack2_hl(av[0], av[1], h, l);
        ((s16x8*)(Ah + srow*40 + skk))[0] = h; ((s16x8*)(Al + srow*40 + skk))[0] = l;
        pack2_hl(av[2], av[3], h, l);
        ((s16x8*)(Ah + srow*40 + skk))[1] = h; ((s16x8*)(Al + srow*40 + skk))[1] = l;
        pack2_hl(bv[0], bv[1], h, l);
        ((s16x8*)(Bh + srow*40 + skk))[0] = h; ((s16x8*)(Bl + srow*40 + skk))[0] = l;
        pack2_hl(bv[2], bv[3], h, l);
        ((s16x8*)(Bh + srow*40 + skk))[1] = h; ((s16x8*)(Bl + srow*40 + skk))[1] = l;
        __syncthreads();
        s16x8 ah[4], al[4], bh[4], bl[4];
#pragma unroll
        for (int mt=0; mt<4; ++mt) {
            ah[mt] = *(const s16x8*)(Ah + (wr + mt*16 + l16)*40 + quad*8);
            al[mt] = *(const s16x8*)(Al + (wr + mt*16 + l16)*40 + quad*8);
        }
#pragma unroll
        for (int nt=0; nt<4; ++nt) {
            bh[nt] = *(const s16x8*)(Bh + (wc + nt*16 + l16)*40 + quad*8);
            bl[nt] = *(const s16x8*)(Bl + (wc + nt*16 + l16)*40 + quad*8);
        }
#pragma unroll
        for (int mt=0; mt<4; ++mt)
#pragma unroll
        for (int nt=0; nt<4; ++nt) {
            acc[mt][nt] = MFMA16(ah[mt], bh[nt], acc[mt][nt]);
            acc[mt][nt] = MFMA16(ah[mt], bl[nt], acc[mt][nt]);
            acc[mt][nt] = MFMA16(al[mt], bh[nt], acc[mt][nt]);
        }
    }
    // row sums (each row staged by thread pair (t, t+1))
    float oA = sumA + __shfl_down(sumA, 1);
    float oB = sumB + __shfl_down(sumB, 1);
    if ((tid & 1) == 0) {
        if (j0 == 0) atomicAdd(&s1[b*256 + i0 + srow], oA);
        if (i0 == 0) atomicAdd(&s0[b*256 + j0 + srow], oB);
    }
    float* outp = partial + (size_t)bid * 16384;
#pragma unroll
    for (int mt=0; mt<4; ++mt)
#pragma unroll
    for (int nt=0; nt<4; ++nt)
#pragma unroll
    for (int r=0; r<4; ++r) {
        int row = wr + mt*16 + quad*4 + r;
        int col = wc + nt*16 + l16;
        outp[row*128 + col] = acc[mt][nt][r];
    }
}

// ---------------- K1r: reduce partials -> M
__global__ __launch_bounds__(256) void k1_reduce(
    const float* __restrict__ partial, float* __restrict__ M)
{
    int gid = blockIdx.x*256 + threadIdx.x;     // 524288
    int b = gid >> 16;
    int rem = gid & 65535;
    int i = rem >> 8, j = rem & 255;
    int ij = ((i>>7)<<1) | (j>>7);
    int idx = (i&127)*128 + (j&127);
    float s = 0.f;
#pragma unroll
    for (int ch = 0; ch < 16; ++ch)
        s += partial[(size_t)((b*16 + ch)*4 + ij)*16384 + idx];
    M[gid] = s;
}

// ---------------- K2m: SA = Tw@s1 ; SP = Pw@s0 + N*pb. grid = 16
__global__ __launch_bounds__(256) void k2m(
    const float* __restrict__ Tw, const float* __restrict__ Pw,
    const float* __restrict__ pb, const float* __restrict__ s0,
    const float* __restrict__ s1, float* __restrict__ SA, float* __restrict__ SP)
{
    __shared__ float sv[256];
    int b = blockIdx.x >> 1, which = blockIdx.x & 1;
    int t = threadIdx.x;
    sv[t] = which ? s0[b*256 + t] : s1[b*256 + t];
    __syncthreads();
    const float* W = which ? Pw : Tw;
    const float* row = W + t*256;
    float acc = 0.f;
    for (int i = 0; i < 256; ++i) acc += row[i] * sv[i];
    if (which) SP[b*256 + t] = acc + 16384.f * pb[t];
    else       SA[b*256 + t] = acc;
}

// ---------------- K2a: P1T[b][d][i] = sum_j Pw[d,j] M[b,i,j]  (hi/lo split)
__global__ __launch_bounds__(256) void k2a(
    const float* __restrict__ Pw, const float* __restrict__ M, float* __restrict__ P1T)
{
    __shared__ short Ah[128*40], Al[128*40], Bh[128*40], Bl[128*40];
    int bid = blockIdx.x;
    int b = bid >> 2, d0 = ((bid>>1)&1)*128, i0 = (bid&1)*128;
    int tid = threadIdx.x;
    int w = tid >> 6, lane = tid & 63;
    int wr = (w >> 1) * 64, wc = (w & 1) * 64;
    int quad = lane >> 4, l16 = lane & 15;
    int srow = tid >> 1, skk = (tid & 1) * 16;

    f32x4 acc[4][4];
#pragma unroll
    for (int i=0;i<4;i++)
#pragma unroll
    for (int j=0;j<4;j++) acc[i][j] = f32x4{0.f,0.f,0.f,0.f};

    for (int s = 0; s < 8; ++s) {
        const float* pa = Pw + (d0 + srow)*256 + s*32 + skk;
        const float* pm = M + (size_t)b*65536 + (i0 + srow)*256 + s*32 + skk;
        f32x4 av[4], bv[4];
#pragma unroll
        for (int q=0;q<4;++q) { av[q] = *(const f32x4*)(pa + q*4); bv[q] = *(const f32x4*)(pm + q*4); }
        __syncthreads();
        s16x8 h, l;
        pack2_hl(av[0], av[1], h, l);
        ((s16x8*)(Ah + srow*40 + skk))[0] = h; ((s16x8*)(Al + srow*40 + skk))[0] = l;
        pack2_hl(av[2], av[3], h, l);
        ((s16x8*)(Ah + srow*40 + skk))[1] = h; ((s16x8*)(Al + srow*40 + skk))[1] = l;
        pack2_hl(bv[0], bv[1], h, l);
        ((s16x8*)(Bh + srow*40 + skk))[0] = h; ((s16x8*)(Bl + srow*40 + skk))[0] = l;
        pack2_hl(bv[2], bv[3], h, l);
        ((s16x8*)(Bh + srow*40 + skk))[1] = h; ((s16x8*)(Bl + srow*40 + skk))[1] = l;
        __syncthreads();
        s16x8 ah[4], al[4], bh[4], bl[4];
#pragma unroll
        for (int mt=0; mt<4; ++mt) {
            ah[mt] = *(const s16x8*)(Ah + (wr + mt*16 + l16)*40 + quad*8);
            al[mt] = *(const s16x8*)(Al + (wr + mt*16 + l16)*40 + quad*8);
        }
#pragma unroll
        for (int nt=0; nt<4; ++nt) {
            bh[nt] = *(const s16x8*)(Bh + (wc + nt*16 + l16)*40 + quad*8);
            bl[nt] = *(const s16x8*)(Bl + (wc + nt*16 + l16)*40 + quad*8);
        }
#pragma unroll
        for (int mt=0; mt<4; ++mt)
#pragma unroll
        for (int nt=0; nt<4; ++nt) {
            acc[mt][nt] = MFMA16(ah[mt], bh[nt], acc[mt][nt]);
            acc[mt][nt] = MFMA16(ah[mt], bl[nt], acc[mt][nt]);
            acc[mt][nt] = MFMA16(al[mt], bh[nt], acc[mt][nt]);
        }
    }
#pragma unroll
    for (int mt=0; mt<4; ++mt)
#pragma unroll
    for (int nt=0; nt<4; ++nt)
#pragma unroll
    for (int r=0; r<4; ++r) {
        int row = wr + mt*16 + quad*4 + r;
        int col = wc + nt*16 + l16;
        P1T[(size_t)b*65536 + (d0+row)*256 + i0 + col] = acc[mt][nt][r];
    }
}

// ---------------- K2b1: f[b][d][c] = sum_i Tw[c,i] P1T[d,i] + biases. tile 256c x 64d
__global__ __launch_bounds__(256) void k2b1(
    const float* __restrict__ Tw, const float* __restrict__ P1T,
    const float* __restrict__ tb, const float* __restrict__ pb,
    const float* __restrict__ SA, const float* __restrict__ SP,
    float* __restrict__ fws)
{
    __shared__ short Ah[256*40], Al[256*40], Bh[64*40], Bl[64*40];
    int bid = blockIdx.x;
    int b = bid >> 2, d0 = (bid & 3)*64;
    int tid = threadIdx.x;
    int w = tid >> 6, lane = tid & 63;
    int quad = lane >> 4, l16 = lane & 15;

    f32x4 acc[4][4];
#pragma unroll
    for (int i=0;i<4;i++)
#pragma unroll
    for (int j=0;j<4;j++) acc[i][j] = f32x4{0.f,0.f,0.f,0.f};

    for (int s = 0; s < 8; ++s) {
        const float* pa = Tw + tid*256 + s*32;
        f32x4 av[8];
#pragma unroll
        for (int q=0;q<8;++q) av[q] = *(const f32x4*)(pa + q*4);
        const float* pbp = P1T + (size_t)b*65536 + (d0 + (tid>>2))*256 + s*32 + (tid&3)*8;
        f32x4 bv0 = *(const f32x4*)(pbp), bv1 = *(const f32x4*)(pbp + 4);
        __syncthreads();
        s16x8 h, l;
#pragma unroll
        for (int q=0;q<4;++q) {
            pack2_hl(av[2*q], av[2*q+1], h, l);
            ((s16x8*)(Ah + tid*40))[q] = h;
            ((s16x8*)(Al + tid*40))[q] = l;
        }
        pack2_hl(bv0, bv1, h, l);
        *(s16x8*)(Bh + (tid>>2)*40 + (tid&3)*8) = h;
        *(s16x8*)(Bl + (tid>>2)*40 + (tid&3)*8) = l;
        __syncthreads();
        s16x8 ah[4], al[4], bh[4], bl[4];
#pragma unroll
        for (int mt=0; mt<4; ++mt) {
            ah[mt] = *(const s16x8*)(Ah + (w*64 + mt*16 + l16)*40 + quad*8);
            al[mt] = *(const s16x8*)(Al + (w*64 + mt*16 + l16)*40 + quad*8);
        }
#pragma unroll
        for (int nt=0; nt<4; ++nt) {
            bh[nt] = *(const s16x8*)(Bh + (nt*16 + l16)*40 + quad*8);
            bl[nt] = *(const s16x8*)(Bl + (nt*16 + l16)*40 + quad*8);
        }
#pragma unroll
        for (int mt=0; mt<4; ++mt)
#pragma unroll
        for (int nt=0; nt<4; ++nt) {
            acc[mt][nt] = MFMA16(ah[mt], bh[nt], acc[mt][nt]);
            acc[mt][nt] = MFMA16(ah[mt], bl[nt], acc[mt][nt]);
            acc[mt][nt] = MFMA16(al[mt], bh[nt], acc[mt][nt]);
        }
    }
#pragma unroll
    for (int mt=0; mt<4; ++mt)
#pragma unroll
    for (int nt=0; nt<4; ++nt)
#pragma unroll
    for (int r=0; r<4; ++r) {
        int c = w*64 + mt*16 + quad*4 + r;
        int d = d0 + nt*16 + l16;
        float fv = acc[mt][nt][r] + tb[c]*SP[b*256 + d] + SA[b*256 + c]*pb[d];
        fws[(size_t)b*65536 + d*256 + c] = fv;
    }
}

// ---------------- K2b2: column softmax (over c) -> F[b][c][d] bf16. grid = 8
__global__ __launch_bounds__(256) void k2b2(
    const float* __restrict__ fws, short* __restrict__ F)
{
    int b = blockIdx.x, d = threadIdx.x;
    const float* fr = fws + (size_t)b*65536 + d*256;
    float mx = -1e30f;
    for (int c=0;c<256;++c) mx = fmaxf(mx, fr[c]);
    float sum = 0.f;
    for (int c=0;c<256;++c) sum += __expf(fr[c] - mx);
    float inv = 1.f / sum;
    for (int c=0;c<256;++c)
        F[(size_t)b*65536 + c*256 + d] = f2bf(__expf(fr[c] - mx) * inv);
}

// ---------------- K2c: G[b][c][e] = sum_d F[c,d] g_w[d,e] ; yb = F@g_b
__global__ __launch_bounds__(256) void k2c(
    const short* __restrict__ F, const short* __restrict__ gwT,
    const float* __restrict__ g_b, short* __restrict__ G, float* __restrict__ yb)
{
    int bid = blockIdx.x;
    int b = bid >> 2, c0 = ((bid>>1)&1)*128, e0 = (bid&1)*128;
    int tid = threadIdx.x;
    int w = tid >> 6, lane = tid & 63;
    int wr = (w >> 1) * 64, wc = (w & 1) * 64;
    int quad = lane >> 4, l16 = lane & 15;

    f32x4 acc[4][4];
#pragma unroll
    for (int i=0;i<4;i++)
#pragma unroll
    for (int j=0;j<4;j++) acc[i][j] = f32x4{0.f,0.f,0.f,0.f};

    for (int s = 0; s < 8; ++s) {
        int k0 = s*32;
        s16x8 af[4], bfr[4];
#pragma unroll
        for (int mt=0; mt<4; ++mt)
            af[mt] = *(const s16x8*)(F + (size_t)b*65536 + (c0 + wr + mt*16 + l16)*256 + k0 + quad*8);
#pragma unroll
        for (int nt=0; nt<4; ++nt)
            bfr[nt] = *(const s16x8*)(gwT + (e0 + wc + nt*16 + l16)*256 + k0 + quad*8);
#pragma unroll
        for (int mt=0; mt<4; ++mt)
#pragma unroll
        for (int nt=0; nt<4; ++nt)
            acc[mt][nt] = MFMA16(af[mt], bfr[nt], acc[mt][nt]);
    }
#pragma unroll
    for (int mt=0; mt<4; ++mt)
#pragma unroll
    for (int nt=0; nt<4; ++nt)
#pragma unroll
    for (int r=0; r<4; ++r) {
        int c = c0 + wr + mt*16 + quad*4 + r;
        int e = e0 + wc + nt*16 + l16;
        G[(size_t)b*65536 + c*256 + e] = f2bf(acc[mt][nt][r]);
    }
    if (e0 == 0 && tid < 128) {
        int c = c0 + tid;
        float a = 0.f;
        const short* fr = F + (size_t)b*65536 + c*256;
        for (int d=0; d<256; ++d) a += bf2f(fr[d]) * g_b[d];
        yb[b*256 + c] = a;
    }
}

// ---------------- K3a: y = G @ x0 + yb, written in scrambled-view layout (bf16)
// grid = 8b * 256 m-blocks (m-block = 64 spatial positions)
__global__ __launch_bounds__(256) void k3a(
    const float* __restrict__ x0, const short* __restrict__ G,
    const float* __restrict__ yb, short* __restrict__ yv)
{
    __shared__ short smX[64*40];
    int bid = blockIdx.x;
    int b = bid >> 8, m0 = (bid & 255) * 64;
    int tid = threadIdx.x;
    int w = tid >> 6, lane = tid & 63;
    int quad = lane >> 4, l16 = lane & 15;
    int rc = w * 64;
    int se = tid >> 3, sm = (tid & 7) * 8;

    const float* px = x0 + (size_t)(b*256 + se)*16384 + m0 + sm;

    f32x4 acc[4][4];
#pragma unroll
    for (int i=0;i<4;i++)
#pragma unroll
    for (int j=0;j<4;j++) acc[i][j] = f32x4{0.f,0.f,0.f,0.f};

    for (int s = 0; s < 8; ++s) {
        int e0 = s*32;
        f32x4 v0 = *(const f32x4*)(px);
        f32x4 v1 = *(const f32x4*)(px + 4);
        px += (size_t)32*16384;
        __syncthreads();
        short hv[8] = {f2bf(v0.x),f2bf(v0.y),f2bf(v0.z),f2bf(v0.w),
                       f2bf(v1.x),f2bf(v1.y),f2bf(v1.z),f2bf(v1.w)};
#pragma unroll
        for (int i=0;i<8;++i) smX[(sm + i)*40 + se] = hv[i];
        __syncthreads();
        s16x8 af[4], bfr[4];
#pragma unroll
        for (int mt=0; mt<4; ++mt)
            af[mt] = *(const s16x8*)(smX + (mt*16 + l16)*40 + quad*8);
#pragma unroll
        for (int nt=0; nt<4; ++nt)
            bfr[nt] = *(const s16x8*)(G + (size_t)b*65536 + (rc + nt*16 + l16)*256 + e0 + quad*8);
#pragma unroll
        for (int mt=0; mt<4; ++mt)
#pragma unroll
        for (int nt=0; nt<4; ++nt)
            acc[mt][nt] = MFMA16(af[mt], bfr[nt], acc[mt][nt]);
    }
    float ybv[4];
#pragma unroll
    for (int nt=0; nt<4; ++nt) ybv[nt] = yb[b*256 + rc + nt*16 + l16];
    short* base = yv + (size_t)b*4194304 + (size_t)m0*256;
#pragma unroll
    for (int mt=0; mt<4; ++mt)
#pragma unroll
    for (int nt=0; nt<4; ++nt)
#pragma unroll
    for (int r=0; r<4; ++r) {
        int m  = mt*16 + quad*4 + r;
        int rr = rc + nt*16 + l16;
        base[m*256 + rr] = f2bf(acc[mt][nt][r] + ybv[nt]);
    }
}

// ---------------- K3b: out = W_w @ y_view + W_b. grid = 8b * 2o * 128n
__global__ __launch_bounds__(256) void k3b(
    const short* __restrict__ yv, const short* __restrict__ Wwb,
    const float* __restrict__ W_b, float* __restrict__ out)
{
    __shared__ short smY[128*40];
    int bid = blockIdx.x;
    int b = bid >> 8, rem = bid & 255;
    int o0 = (rem >> 7) * 128, n0 = (rem & 127) * 128;
    int tid = threadIdx.x;
    int w = tid >> 6, lane = tid & 63;
    int wr = (w >> 1) * 64, wc = (w & 1) * 64;
    int quad = lane >> 4, l16 = lane & 15;
    int sc = tid >> 3, sn = (tid & 7) * 16;

    const short* py = yv + (size_t)b*4194304 + (size_t)sc*16384 + n0 + sn;

    f32x4 acc[4][4];
#pragma unroll
    for (int i=0;i<4;i++)
#pragma unroll
    for (int j=0;j<4;j++) acc[i][j] = f32x4{0.f,0.f,0.f,0.f};

    for (int s = 0; s < 8; ++s) {
        int c0 = s*32;
        s16x8 y0 = *(const s16x8*)(py);
        s16x8 y1 = *(const s16x8*)(py + 8);
        py += (size_t)32*16384;
        __syncthreads();
#pragma unroll
        for (int i=0;i<8;++i) { smY[(sn + i)*40 + sc] = y0[i]; smY[(sn + 8 + i)*40 + sc] = y1[i]; }
        __syncthreads();
        s16x8 af[4], bfr[4];
#pragma unroll
        for (int mt=0; mt<4; ++mt)
            af[mt] = *(const s16x8*)(Wwb + (o0 + wr + mt*16 + l16)*256 + c0 + quad*8);
#pragma unroll
        for (int nt=0; nt<4; ++nt)
            bfr[nt] = *(const s16x8*)(smY + (wc + nt*16 + l16)*40 + quad*8);
#pragma unroll
        for (int mt=0; mt<4; ++mt)
#pragma unroll
        for (int nt=0; nt<4; ++nt)
            acc[mt][nt] = MFMA16(af[mt], bfr[nt], acc[mt][nt]);
    }
#pragma unroll
    for (int mt=0; mt<4; ++mt)
#pragma unroll
    for (int nt=0; nt<4; ++nt)
#pragma unroll
    for (int r=0; r<4; ++r) {
        int o  = o0 + wr + mt*16 + quad*4 + r;
        int nn = n0 + wc + nt*16 + l16;
        out[(size_t)(b*256 + o)*16384 + nn] = acc[mt][nt][r] + W_b[o];
    }
}

extern "C" void kernel_launch(void* const* d_in, const int* in_sizes, int n_in,
                              void* d_out, int out_size, void* d_ws, size_t ws_size,
                              hipStream_t stream)
{
    (void)in_sizes; (void)n_in; (void)out_size; (void)ws_size;
    const float* x0   = (const float*)d_in[0];
    const float* x1   = (const float*)d_in[1];
    const float* g_w  = (const float*)d_in[2];
    const float* g_b  = (const float*)d_in[3];
    const float* th_w = (const float*)d_in[4];
    const float* th_b = (const float*)d_in[5];
    const float* ph_w = (const float*)d_in[6];
    const float* ph_b = (const float*)d_in[7];
    const float* W_w  = (const float*)d_in[8];
    const float* W_b  = (const float*)d_in[9];
    float* out = (float*)d_out;

    char* ws = (char*)d_ws;
    short* yv      = (short*)(ws + 0);          // 67108864 B (aliases partial)
    float* partial = (float*)(ws + 0);          // 33554432 B, dead after k1_reduce
    float* M       = (float*)(ws + 67108864);   // 2 MB
    float* P1T     = (float*)(ws + 69206016);   // 2 MB
    float* fws     = (float*)(ws + 71303168);   // 2 MB
    short* F       = (short*)(ws + 73400320);   // 1 MB
    short* G       = (short*)(ws + 74448896);   // 1 MB
    short* gwT     = (short*)(ws + 75497472);   // 128 KB
    short* Wwb     = (short*)(ws + 75628544);   // 128 KB
    float* s0      = (float*)(ws + 75759616);
    float* s1      = (float*)(ws + 75767808);
    float* SA      = (float*)(ws + 75776000);
    float* SP      = (float*)(ws + 75784192);
    float* yb      = (float*)(ws + 75792384);

    k0_prep  <<<dim3(256),  dim3(256), 0, stream>>>(g_w, W_w, gwT, Wwb, s0, s1);
    k1_gram  <<<dim3(512),  dim3(256), 0, stream>>>(x0, x1, partial, s0, s1);
    k1_reduce<<<dim3(2048), dim3(256), 0, stream>>>(partial, M);
    k2m      <<<dim3(16),   dim3(256), 0, stream>>>(th_w, ph_w, ph_b, s0, s1, SA, SP);
    k2a      <<<dim3(32),   dim3(256), 0, stream>>>(ph_w, M, P1T);
    k2b1     <<<dim3(32),   dim3(256), 0, stream>>>(th_w, P1T, th_b, ph_b, SA, SP, fws);
    k2b2     <<<dim3(8),    dim3(256), 0, stream>>>(fws, F);
    k2c      <<<dim3(32),   dim3(256), 0, stream>>>(F, gwT, g_b, G, yb);
    k3a      <<<dim3(2048), dim3(256), 0, stream>>>(x0, G, yb, yv);
    k3b      <<<dim3(2048), dim3(256), 0, stream>>>(yv, Wwb, W_b, out);
}